// Round 18
// baseline (405.817 us; speedup 1.0000x reference)
//
#include <hip/hip_runtime.h>
#include <math.h>

#define BLOCK 256

typedef __attribute__((ext_vector_type(8))) short bf16x8;
typedef __attribute__((ext_vector_type(4))) float f32x4;
typedef __attribute__((ext_vector_type(16))) float f32x16;

// fp32 -> bf16 round-to-nearest-even (finite inputs)
static __device__ __forceinline__ unsigned short f2bf(float x) {
  unsigned u = __builtin_bit_cast(unsigned, x);
  u = (u + 0x7FFFu + ((u >> 16) & 1u)) >> 16;
  return (unsigned short)u;
}
static __device__ __forceinline__ float bf2f(unsigned short b) {
  return __builtin_bit_cast(float, (unsigned)b << 16);
}
static __device__ __forceinline__ unsigned pk2bf(float lo, float hi) {
  return (unsigned)f2bf(lo) | ((unsigned)f2bf(hi) << 16);
}

// ---------------------------------------------------------------------------
// Prep: fp32 KxK weights -> bf16 FRAGMENT-NATIVE layout in ws (R17 proven).
// Per 32-k chunk (bytes CHB = (K/32)*2048), per 32-col tile (2048 B):
//   byte = chunk*CHB + tile*2048 + q*1024 + lane*16 + idx*2
// where lane = hA*32+rA (rA = col%32, hA = (k%16)/8), q = (k%32)/16,
// idx = k%8.  A wave's bf16x8 B-fragment load is a single coalesced 1KB
// segment: addr = base + lane*16.
// ---------------------------------------------------------------------------
__global__ __launch_bounds__(BLOCK) void prep_w(
    const float* __restrict__ w0, const float* __restrict__ w1,
    const float* __restrict__ w2, const float* __restrict__ w3,
    const float* __restrict__ w4, const float* __restrict__ w5,
    const float* __restrict__ w6, const float* __restrict__ w7,
    unsigned short* __restrict__ wsU)
{
  const int bpm[8]  = {64, 64, 16, 16, 4, 4, 1, 1};   // 1024 elems per block
  const int ks[8]   = {256, 256, 128, 128, 64, 64, 32, 32};
  const size_t doffB[8] = {0ull, 131072ull, 262144ull, 294912ull,
                           327680ull, 335872ull, 344064ull, 346112ull};
  const int chb[8] = {16384, 16384, 8192, 8192, 4096, 4096, 2048, 2048};
  const float* srcs[8] = {w0, w1, w2, w3, w4, w5, w6, w7};

  int m = 0, sub = blockIdx.x;
  while (m < 7 && sub >= bpm[m]) { sub -= bpm[m]; ++m; }
  const int K = ks[m];
  const int e = sub * 1024 + threadIdx.x * 4;
  const float4 v = *(const float4*)&srcs[m][e];
  const int k = e / K, c = e % K;
  const int chunk = k >> 5, kk = k & 31;
  const int tile = c >> 5, rA = c & 31;
  const int q = kk >> 4, hA = (kk >> 3) & 1, idx = kk & 7;
  const size_t d0 = doffB[m] / 2 + (size_t)chunk * (chb[m] / 2)
                  + (size_t)tile * 1024 + q * 512 + (hA * 32 + rA) * 8 + idx;
  wsU[d0]      = f2bf(v.x);
  wsU[d0 + 8]  = f2bf(v.y);
  wsU[d0 + 16] = f2bf(v.z);
  wsU[d0 + 24] = f2bf(v.w);
}

// ---------------------------------------------------------------------------
// REGISTER-DIRECT block GEMM: C[MP x K] = XB[MP x K](bf16 LDS) @ W(K x K).
// B-fragments loaded straight from global ws (fragment-native, L2-hot) —
// no LDS weight buffer, no staging barriers. kc-loop fully unrolled.
// MODE 0: XB <- bf16(C) in place;  2: XB <- bf16(C*C) (l=0 tp);
// MODE 3: out[obase+row*K+col] = fres[...] + C.  (R17 proven.)
// ---------------------------------------------------------------------------
template<int K, int MP, int MR, int SX, int CG, int MODE, int CH, int CHB>
__device__ __forceinline__ void gemm_direct(
    int tid, unsigned short* XB, const char* __restrict__ Wg,
    const float* __restrict__ fres, float* __restrict__ outg, size_t obase)
{
  constexpr int RG = 4 / CG;                  // waves tiling M (4 waves total)
  constexpr int MT = MP / 32, NT = K / 32;
  constexpr int MTW = (MT + RG - 1) / RG, NTW = NT / CG;
  const int lane = tid & 63, wave = tid >> 6;
  const int wgn = wave % CG, wgm = wave / CG;
  const int rA = lane & 31, hA = lane >> 5;

  f32x16 acc[MTW][NTW] = {};

#pragma unroll
  for (int kc = 0; kc < CH; ++kc) {
    bf16x8 bfr[NTW][2], afr[MTW][2];
#pragma unroll
    for (int ni = 0; ni < NTW; ++ni)
#pragma unroll
      for (int q = 0; q < 2; ++q)
        bfr[ni][q] = *(const bf16x8*)(Wg + (size_t)kc * CHB
            + (wgn + ni * CG) * 2048 + q * 1024 + lane * 16);
#pragma unroll
    for (int mi = 0; mi < MTW; ++mi) {
      const int mt = wgm + mi * RG;
      if (mt < MT) {
#pragma unroll
        for (int q = 0; q < 2; ++q)
          afr[mi][q] = *(const bf16x8*)&XB[(mt * 32 + rA) * SX + kc * 32 + q * 16 + hA * 8];
      }
    }
    __builtin_amdgcn_s_setprio(1);
#pragma unroll
    for (int mi = 0; mi < MTW; ++mi) {
      const int mt = wgm + mi * RG;
      if (mt < MT) {
#pragma unroll
        for (int ni = 0; ni < NTW; ++ni)
#pragma unroll
          for (int q = 0; q < 2; ++q)
            acc[mi][ni] = __builtin_amdgcn_mfma_f32_32x32x16_bf16(
                afr[mi][q], bfr[ni][q], acc[mi][ni], 0, 0, 0);
      }
    }
    __builtin_amdgcn_s_setprio(0);
  }

  // In-place XB modes: ALL waves' XB reads must complete before writing.
  if constexpr (MODE != 3) __syncthreads();

  // epilogue (C/D: col = lane&31, row = (r&3) + 8*(r>>2) + 4*(lane>>5))
#pragma unroll
  for (int mi = 0; mi < MTW; ++mi) {
    const int mt = wgm + mi * RG;
    if (mt >= MT) continue;
#pragma unroll
    for (int ni = 0; ni < NTW; ++ni) {
      const int col = (wgn + ni * CG) * 32 + rA;
#pragma unroll
      for (int r = 0; r < 16; ++r) {
        const int row = mt * 32 + (r & 3) + ((r >> 2) << 3) + (hA << 2);
        const float v = acc[mi][ni][r];
        if constexpr (MODE == 0) {
          if (row < MR) XB[row * SX + col] = f2bf(v);
        } else if constexpr (MODE == 2) {
          if (row < MR) XB[row * SX + col] = f2bf(v * v);
        } else {
          if (row < MR) {
            const size_t o = obase + (size_t)row * K + col;
            outg[o] = fres[o] + v;
          }
        }
      }
    }
  }
}

// ---------------------------------------------------------------------------
// tp phase, 2-channel vectorized (requires (A*K/2) % BLOCK == 0).
// ---------------------------------------------------------------------------
template<int D, int K, int A, int SX>
static __device__ __forceinline__ void tp_pair(int tid, unsigned short* XB) {
  constexpr int DD = D * D;
  constexpr int K2 = K / 2;
  constexpr int PAIRS2 = A * K2;
  static_assert(PAIRS2 % BLOCK == 0, "tp2 coverage");
  const float rsD = rsqrtf((float)D);
#pragma unroll
  for (int it = 0; it < PAIRS2 / BLOCK; ++it) {
    const int p = tid + it * BLOCK;
    const int aa = p / K2, c2 = (p % K2) * 2;
    float hv0[DD], hv1[DD];
#pragma unroll
    for (int r = 0; r < DD; ++r) {
      const unsigned u = *(const unsigned*)&XB[(aa * DD + r) * SX + c2];
      hv0[r] = bf2f((unsigned short)u);
      hv1[r] = bf2f((unsigned short)(u >> 16));
    }
#pragma unroll
    for (int i2 = 0; i2 < D; ++i2)
#pragma unroll
      for (int k2 = 0; k2 < D; ++k2) {
        float s0 = 0.f, s1 = 0.f;
#pragma unroll
        for (int jj = 0; jj < D; ++jj) {
          s0 += hv0[i2 * D + jj] * hv0[jj * D + k2];
          s1 += hv1[i2 * D + jj] * hv1[jj * D + k2];
        }
        *(unsigned*)&XB[(aa * DD + i2 * D + k2) * SX + c2] =
            pk2bf(s0 * rsD, s1 * rsD);
      }
  }
}

// tp phase, scalar one-thread-per-column (requires (A*K) % BLOCK == 0).
template<int D, int K, int A, int SX>
static __device__ __forceinline__ void tp_scalar(int tid, unsigned short* XB) {
  constexpr int DD = D * D;
  constexpr int PAIRS = A * K;
  static_assert(PAIRS % BLOCK == 0, "tp coverage");
  const float rsD = rsqrtf((float)D);
#pragma unroll
  for (int it = 0; it < PAIRS / BLOCK; ++it) {
    const int p = tid + it * BLOCK;
    const int aa = p / K, c = p % K;
    float hv[DD];
#pragma unroll
    for (int r = 0; r < DD; ++r) hv[r] = bf2f(XB[(aa * DD + r) * SX + c]);
#pragma unroll
    for (int i2 = 0; i2 < D; ++i2)
#pragma unroll
      for (int k2 = 0; k2 < D; ++k2) {
        float s = 0.f;
#pragma unroll
        for (int jj = 0; jj < D; ++jj) s += hv[i2 * D + jj] * hv[jj * D + k2];
        XB[(aa * DD + i2 * D + k2) * SX + c] = f2bf(s * rsD);
      }
  }
}

// tp phase, two lanes per column (requires A*K*2 == BLOCK; R3-R14 proven).
// Both lanes of a pair are in the SAME wave -> lockstep: all reads complete
// before any write of the same pair.
template<int D, int K, int A, int SX>
static __device__ __forceinline__ void tp_twolane(int tid, unsigned short* XB) {
  constexpr int DD = D * D;
  constexpr int PAIRS = A * K;
  static_assert(PAIRS * 2 == BLOCK, "tp two-lane coverage");
  const float rsD = rsqrtf((float)D);
  const int p = tid >> 1, half = tid & 1;
  const int aa = p / K, c = p % K;
  float hv[DD];
#pragma unroll
  for (int r = 0; r < DD; ++r) hv[r] = bf2f(XB[(aa * DD + r) * SX + c]);
  const int i0 = half ? (D / 2 + 1) : 0;
  const int i1 = half ? D : (D / 2 + 1);
  for (int i2 = i0; i2 < i1; ++i2)
#pragma unroll
    for (int k2 = 0; k2 < D; ++k2) {
      float s = 0.f;
#pragma unroll
      for (int jj = 0; jj < D; ++jj) s += hv[i2 * D + jj] * hv[jj * D + k2];
      XB[(aa * DD + i2 * D + k2) * SX + c] = f2bf(s * rsD);
    }
}

// ---------------------------------------------------------------------------
// Unified per-degree fused CG body (all degrees): LDS = XB only.
//   out = f + linear(tp(linear(rmsnorm(f)*wr, wi)), wo)
// ---------------------------------------------------------------------------
template<int D, int K, int A, int MP, int CG, int CH, int CHB, int MODE1>
__device__ __forceinline__ void cg_body_d(
    int bid, const float* __restrict__ f, const float* __restrict__ wr,
    const char* __restrict__ wiw, const char* __restrict__ wow,
    float* __restrict__ out, unsigned char* SMEM)
{
  constexpr int DD  = D * D;
  constexpr int MR  = A * DD;
  constexpr int SX  = K + 8;
  constexpr int TPA = BLOCK / A;
  constexpr int NF4 = DD * K / 4;
  constexpr int CEIL = (NF4 + TPA - 1) / TPA;

  unsigned short* XB = (unsigned short*)SMEM;

  const int tid = threadIdx.x;
  const int nbase = bid * A;
  const size_t obase = (size_t)nbase * DD * K;

  // ---- P1: reg-stage f, per-atom RMS ----
  const int a = tid / TPA, j = tid % TPA;
  const float* fa = f + (size_t)(nbase + a) * DD * K;
  float4 vreg[CEIL];
  float ss = 0.f;
#pragma unroll
  for (int it = 0; it < CEIL; ++it) {
    const int i = j + it * TPA;
    if (i < NF4) {
      vreg[it] = *(const float4*)&fa[i * 4];
      ss += vreg[it].x * vreg[it].x + vreg[it].y * vreg[it].y +
            vreg[it].z * vreg[it].z + vreg[it].w * vreg[it].w;
    }
  }
#pragma unroll
  for (int o = TPA >> 1; o >= 1; o >>= 1) ss += __shfl_xor(ss, o, 64);
  const float inv = rsqrtf(ss / (float)(DD * K) + 1e-6f);

  // ---- P2: XB = bf16(f * inv * wr), wr straight from global (L2-hot) ----
#pragma unroll
  for (int it = 0; it < CEIL; ++it) {
    const int i = j + it * TPA;
    if (i < NF4) {
      const int e = i * 4, m = e / K, c = e % K;
      const float4 w4 = *(const float4*)&wr[c];
      const unsigned long long pk =
          (unsigned long long)f2bf(vreg[it].x * inv * w4.x) |
          ((unsigned long long)f2bf(vreg[it].y * inv * w4.y) << 16) |
          ((unsigned long long)f2bf(vreg[it].z * inv * w4.z) << 32) |
          ((unsigned long long)f2bf(vreg[it].w * inv * w4.w) << 48);
      *(unsigned long long*)&XB[(a * DD + m) * SX + c] = pk;
    }
  }
  __syncthreads();  // XB(xn) visible to all waves

  // ---- GEMM1: h = xn @ wi -> XB in place (bf16; squared for D==1) ----
  gemm_direct<K, MP, MR, SX, CG, MODE1, CH, CHB>(
      tid, XB, wiw, nullptr, nullptr, 0);
  __syncthreads();  // h visible

  // ---- tp: t = (h h)/sqrt(D) -> XB in place ----
  if constexpr (D > 1) {
    if constexpr ((A * K / 2) % BLOCK == 0) {
      tp_pair<D, K, A, SX>(tid, XB);
    } else if constexpr ((A * K) % BLOCK == 0) {
      tp_scalar<D, K, A, SX>(tid, XB);
    } else {
      tp_twolane<D, K, A, SX>(tid, XB);
    }
    __syncthreads();  // XB(t) ready
  }

  // ---- GEMM2: out = f + t @ wo ----
  gemm_direct<K, MP, MR, SX, CG, 3, CH, CHB>(
      tid, XB, wow, f, out, obase);
}

// ---------------------------------------------------------------------------
// Mega-kernel, degree-interleaved (anti-convoy): counts l0:l1:l2:l3 =
// 625:2500:2500:5000 = 1:4:4:8 -> period-17 pattern x 625 = 10625 blocks.
// LDS = XB only: l0 16896, l1 26112, l2 32256 (union max), l3 17920
// -> 5 blocks/CU (20 waves). VGPR cap 102 via launch_bounds(256,5).
// ---------------------------------------------------------------------------
__global__ __launch_bounds__(BLOCK, 5) void cg_mega(
    const float* __restrict__ f0, const float* __restrict__ wr0,
    const float* __restrict__ f1, const float* __restrict__ wr1,
    const float* __restrict__ f2, const float* __restrict__ wr2,
    const float* __restrict__ f3, const float* __restrict__ wr3,
    const char* __restrict__ wsB,
    float* __restrict__ out0, float* __restrict__ out1,
    float* __restrict__ out2, float* __restrict__ out3)
{
  __shared__ __align__(16) unsigned char SMEM[32256];
  const int b = blockIdx.x;
  const int p = b / 17, r = b % 17;
  if (r == 0) {
    // <D,K,A,MP,CG,CH,CHB,MODE1>
    cg_body_d<1, 256, 32,  32, 4, 8, 16384, 2>(
        p, f0, wr0, wsB + 0, wsB + 131072, out0, SMEM);
  } else if (r < 5) {
    cg_body_d<3, 128,  8,  96, 4, 4,  8192, 0>(
        p * 4 + (r - 1), f1, wr1, wsB + 262144, wsB + 294912, out1, SMEM);
  } else if (r < 9) {
    cg_body_d<5,  64,  8, 224, 2, 2,  4096, 0>(
        p * 4 + (r - 5), f2, wr2, wsB + 327680, wsB + 335872, out2, SMEM);
  } else {
    // l3: A=4, MP=224 (R8-proven geometry), tp two-lane (A*K*2 == BLOCK)
    cg_body_d<7,  32,  4, 224, 1, 1,  2048, 0>(
        p * 8 + (r - 9), f3, wr3, wsB + 344064, wsB + 346112, out3, SMEM);
  }
}

// ===========================================================================
// Fallback (round-2, proven): used only if ws_size is too small for prep.
// ===========================================================================
template<int K, int MP, int MR, int SX, int SH, int WGM, int WGN, int MTW, int NTW, bool FINAL>
__device__ __forceinline__ void fb_gemm(
    int tid, const unsigned short* __restrict__ XB, float* __restrict__ Hs,
    unsigned short* __restrict__ WTl, const float* __restrict__ Wg,
    const float* __restrict__ fres, float* __restrict__ out, size_t obase)
{
  constexpr int TM = MP / 16;
  constexpr int WSTR = 40;
  const int lane = tid & 63;
  const int wave = tid >> 6;
  const int wgn = wave % WGN;
  const int wgm = wave / WGN;
  const int rl = lane & 15;
  const int kl = (lane >> 4) * 8;
  const int rit = (lane >> 4) * 4;
  const int cit = lane & 15;

  f32x4 acc[MTW][NTW];
#pragma unroll
  for (int mi = 0; mi < MTW; ++mi)
#pragma unroll
    for (int ni = 0; ni < NTW; ++ni) acc[mi][ni] = f32x4{0.f, 0.f, 0.f, 0.f};

  for (int kc = 0; kc < K / 32; ++kc) {
    __syncthreads();
    for (int i = tid; i < 32 * K; i += BLOCK) {
      const int kk = i / K, c = i % K;
      WTl[c * WSTR + kk] = f2bf(Wg[(size_t)(kc * 32 + kk) * K + c]);
    }
    __syncthreads();
    bf16x8 bfr[NTW], afr[MTW];
#pragma unroll
    for (int ni = 0; ni < NTW; ++ni) {
      const int col = (wgn + ni * WGN) * 16 + rl;
      bfr[ni] = *(const bf16x8*)&WTl[col * WSTR + kl];
    }
#pragma unroll
    for (int mi = 0; mi < MTW; ++mi) {
      const int mt = wgm + mi * WGM;
      if (mt < TM) afr[mi] = *(const bf16x8*)&XB[(mt * 16 + rl) * SX + kc * 32 + kl];
    }
#pragma unroll
    for (int mi = 0; mi < MTW; ++mi) {
      const int mt = wgm + mi * WGM;
      if (mt < TM) {
#pragma unroll
        for (int ni = 0; ni < NTW; ++ni)
          acc[mi][ni] = __builtin_amdgcn_mfma_f32_16x16x32_bf16(afr[mi], bfr[ni], acc[mi][ni], 0, 0, 0);
      }
    }
  }
#pragma unroll
  for (int mi = 0; mi < MTW; ++mi) {
    const int mt = wgm + mi * WGM;
    if (mt >= TM) continue;
#pragma unroll
    for (int ni = 0; ni < NTW; ++ni) {
      const int col = (wgn + ni * WGN) * 16 + cit;
#pragma unroll
      for (int r = 0; r < 4; ++r) {
        const int row = mt * 16 + rit + r;
        if constexpr (!FINAL) {
          Hs[row * SH + col] = acc[mi][ni][r];
        } else {
          if (row < MR) {
            const size_t o = obase + (size_t)row * K + col;
            out[o] = fres[o] + acc[mi][ni][r];
          }
        }
      }
    }
  }
}

template<int D, int K, int A, int MP, int WGM, int WGN, int MTW, int NTW>
__global__ __launch_bounds__(BLOCK) void cg_mfma_fb(
    const float* __restrict__ f, const float* __restrict__ wr,
    const float* __restrict__ wi, const float* __restrict__ wo,
    float* __restrict__ out)
{
  constexpr int DD = D * D;
  constexpr int MR = A * DD;
  constexpr int SX = K + 8;
  constexpr int SH = K + 4;
  constexpr int TPA = BLOCK / A;
  constexpr int WSTR = 40;

  __shared__ __align__(16) unsigned short XB[MP * SX];
  __shared__ __align__(16) float H[MP * SH];
  __shared__ __align__(16) unsigned short WTl[K * WSTR];
  __shared__ float s_inv[A];

  const int tid = threadIdx.x;
  const int nbase = blockIdx.x * A;
  const size_t obase = (size_t)nbase * DD * K;

  if constexpr (MP > MR) {
    for (int i = tid; i < (MP - MR) * K; i += BLOCK)
      XB[(MR + i / K) * SX + (i % K)] = 0;
  }
  {
    const int a = tid / TPA, j = tid % TPA;
    const float4* fap = (const float4*)(f + (size_t)(nbase + a) * DD * K);
    constexpr int NF4 = DD * K / 4;
    float ss = 0.f;
    for (int i = j; i < NF4; i += TPA) {
      const float4 v = fap[i];
      const int e = i * 4, m = e / K, c = e % K;
      *(float4*)&H[(a * DD + m) * SH + c] = v;
      ss += v.x * v.x + v.y * v.y + v.z * v.z + v.w * v.w;
    }
#pragma unroll
    for (int o = TPA >> 1; o >= 1; o >>= 1) ss += __shfl_xor(ss, o, 64);
    if (j == 0) s_inv[a] = rsqrtf(ss / (float)(DD * K) + 1e-6f);
  }
  __syncthreads();
  for (int i2 = tid; i2 < MR * K / 2; i2 += BLOCK) {
    const int e = i2 * 2, m = e / K, c = e % K;
    const float2 v = *(const float2*)&H[m * SH + c];
    const float2 wv = *(const float2*)&wr[c];
    const float s = s_inv[m / DD];
    const unsigned lo = f2bf(v.x * s * wv.x);
    const unsigned hi = f2bf(v.y * s * wv.y);
    *(unsigned*)&XB[m * SX + c] = lo | (hi << 16);
  }
  fb_gemm<K, MP, MR, SX, SH, WGM, WGN, MTW, NTW, false>(
      tid, XB, H, WTl, wi, nullptr, nullptr, 0);
  __syncthreads();
  {
    const float rsD = rsqrtf((float)D);
    for (int base = 0; base < A * K; base += BLOCK) {
      const int t2 = base + tid;
      if (t2 < A * K) {
        const int aa = t2 / K, c = t2 % K;
        float hv[DD];
#pragma unroll
        for (int r = 0; r < DD; ++r) hv[r] = H[(aa * DD + r) * SH + c];
#pragma unroll
        for (int i = 0; i < D; ++i)
#pragma unroll
          for (int k2 = 0; k2 < D; ++k2) {
            float s = 0.f;
#pragma unroll
            for (int jj = 0; jj < D; ++jj) s += hv[i * D + jj] * hv[jj * D + k2];
            XB[(aa * DD + i * D + k2) * SX + c] = f2bf(s * rsD);
          }
      }
    }
  }
  fb_gemm<K, MP, MR, SX, SH, WGM, WGN, MTW, NTW, true>(
      tid, XB, nullptr, WTl, wo, f, out, obase);
}

// ===========================================================================
extern "C" void kernel_launch(void* const* d_in, const int* in_sizes, int n_in,
                              void* d_out, int out_size, void* d_ws, size_t ws_size,
                              hipStream_t stream)
{
  (void)in_sizes; (void)n_in; (void)out_size;
  const float* f0  = (const float*)d_in[0];
  const float* wr0 = (const float*)d_in[1];
  const float* wi0 = (const float*)d_in[2];
  const float* wo0 = (const float*)d_in[3];
  const float* f1  = (const float*)d_in[4];
  const float* wr1 = (const float*)d_in[5];
  const float* wi1 = (const float*)d_in[6];
  const float* wo1 = (const float*)d_in[7];
  const float* f2  = (const float*)d_in[8];
  const float* wr2 = (const float*)d_in[9];
  const float* wi2 = (const float*)d_in[10];
  const float* wo2 = (const float*)d_in[11];
  const float* f3  = (const float*)d_in[12];
  const float* wr3 = (const float*)d_in[13];
  const float* wi3 = (const float*)d_in[14];
  const float* wo3 = (const float*)d_in[15];

  float* out  = (float*)d_out;
  float* out0 = out;
  float* out1 = out0 + (size_t)20000 * 256;
  float* out2 = out1 + (size_t)20000 * 1152;
  float* out3 = out2 + (size_t)20000 * 1600;

  if (ws_size >= 348160) {
    unsigned short* wsU = (unsigned short*)d_ws;
    const char* wsB = (const char*)d_ws;
    prep_w<<<170, BLOCK, 0, stream>>>(wi0, wo0, wi1, wo1, wi2, wo2, wi3, wo3, wsU);
    cg_mega<<<10625, BLOCK, 0, stream>>>(
        f0, wr0, f1, wr1, f2, wr2, f3, wr3, wsB, out0, out1, out2, out3);
  } else {
    cg_mfma_fb<1, 256, 32,  32, 1, 4, 2, 4><<< 625, BLOCK, 0, stream>>>(f0, wr0, wi0, wo0, out0);
    cg_mfma_fb<3, 128,  8,  80, 1, 4, 5, 2><<<2500, BLOCK, 0, stream>>>(f1, wr1, wi1, wo1, out1);
    cg_mfma_fb<5,  64,  4, 112, 1, 4, 7, 1><<<5000, BLOCK, 0, stream>>>(f2, wr2, wi2, wo2, out2);
    cg_mfma_fb<7,  32,  4, 208, 4, 1, 4, 2><<<5000, BLOCK, 0, stream>>>(f3, wr3, wi3, wo3, out3);
  }
}

// Round 19
// 235.311 us; speedup vs baseline: 1.7246x; 1.7246x over previous
//
#include <hip/hip_runtime.h>
#include <math.h>

#define BLOCK 256

typedef __attribute__((ext_vector_type(8))) short bf16x8;
typedef __attribute__((ext_vector_type(4))) float f32x4;
typedef __attribute__((ext_vector_type(16))) float f32x16;

// fp32 -> bf16 round-to-nearest-even (finite inputs)
static __device__ __forceinline__ unsigned short f2bf(float x) {
  unsigned u = __builtin_bit_cast(unsigned, x);
  u = (u + 0x7FFFu + ((u >> 16) & 1u)) >> 16;
  return (unsigned short)u;
}
static __device__ __forceinline__ float bf2f(unsigned short b) {
  return __builtin_bit_cast(float, (unsigned)b << 16);
}
static __device__ __forceinline__ unsigned pk2bf(float lo, float hi) {
  return (unsigned)f2bf(lo) | ((unsigned)f2bf(hi) << 16);
}

// ---------------------------------------------------------------------------
// Prep: fp32 KxK weights -> bf16 FRAGMENT-NATIVE layout in ws (R17 proven).
// Per 32-k chunk (bytes CHB = (K/32)*2048), per 32-col tile (2048 B):
//   byte = chunk*CHB + tile*2048 + q*1024 + lane*16 + idx*2
// where lane = hA*32+rA (rA = col%32, hA = (k%16)/8), q = (k%32)/16,
// idx = k%8.  A wave's bf16x8 B-fragment load is a single coalesced 1KB
// segment: addr = base + lane*16.
// ---------------------------------------------------------------------------
__global__ __launch_bounds__(BLOCK) void prep_w(
    const float* __restrict__ w0, const float* __restrict__ w1,
    const float* __restrict__ w2, const float* __restrict__ w3,
    const float* __restrict__ w4, const float* __restrict__ w5,
    const float* __restrict__ w6, const float* __restrict__ w7,
    unsigned short* __restrict__ wsU)
{
  const int bpm[8]  = {64, 64, 16, 16, 4, 4, 1, 1};   // 1024 elems per block
  const int ks[8]   = {256, 256, 128, 128, 64, 64, 32, 32};
  const size_t doffB[8] = {0ull, 131072ull, 262144ull, 294912ull,
                           327680ull, 335872ull, 344064ull, 346112ull};
  const int chb[8] = {16384, 16384, 8192, 8192, 4096, 4096, 2048, 2048};
  const float* srcs[8] = {w0, w1, w2, w3, w4, w5, w6, w7};

  int m = 0, sub = blockIdx.x;
  while (m < 7 && sub >= bpm[m]) { sub -= bpm[m]; ++m; }
  const int K = ks[m];
  const int e = sub * 1024 + threadIdx.x * 4;
  const float4 v = *(const float4*)&srcs[m][e];
  const int k = e / K, c = e % K;
  const int chunk = k >> 5, kk = k & 31;
  const int tile = c >> 5, rA = c & 31;
  const int q = kk >> 4, hA = (kk >> 3) & 1, idx = kk & 7;
  const size_t d0 = doffB[m] / 2 + (size_t)chunk * (chb[m] / 2)
                  + (size_t)tile * 1024 + q * 512 + (hA * 32 + rA) * 8 + idx;
  wsU[d0]      = f2bf(v.x);
  wsU[d0 + 8]  = f2bf(v.y);
  wsU[d0 + 16] = f2bf(v.z);
  wsU[d0 + 24] = f2bf(v.w);
}

// ---------------------------------------------------------------------------
// REGISTER-DIRECT block GEMM: C[MP x K] = XB[MP x K](bf16 LDS) @ W(K x K).
// B-fragments loaded straight from global ws (fragment-native, L2-hot) —
// no LDS weight buffer, no staging barriers. kc-loop fully unrolled so the
// compiler software-pipelines the global loads under the MFMAs.
// MODE 0: XB <- bf16(C) in place;  2: XB <- bf16(C*C) (l=0 tp);
// MODE 3: out[obase+row*K+col] = fres[...] + C.  (R17 proven.)
// ---------------------------------------------------------------------------
template<int K, int MP, int MR, int SX, int CG, int MODE, int CH, int CHB>
__device__ __forceinline__ void gemm_direct(
    int tid, unsigned short* XB, const char* __restrict__ Wg,
    const float* __restrict__ fres, float* __restrict__ outg, size_t obase)
{
  constexpr int RG = 4 / CG;                  // waves tiling M (4 waves total)
  constexpr int MT = MP / 32, NT = K / 32;
  constexpr int MTW = (MT + RG - 1) / RG, NTW = NT / CG;
  const int lane = tid & 63, wave = tid >> 6;
  const int wgn = wave % CG, wgm = wave / CG;
  const int rA = lane & 31, hA = lane >> 5;

  f32x16 acc[MTW][NTW] = {};

#pragma unroll
  for (int kc = 0; kc < CH; ++kc) {
    bf16x8 bfr[NTW][2], afr[MTW][2];
#pragma unroll
    for (int ni = 0; ni < NTW; ++ni)
#pragma unroll
      for (int q = 0; q < 2; ++q)
        bfr[ni][q] = *(const bf16x8*)(Wg + (size_t)kc * CHB
            + (wgn + ni * CG) * 2048 + q * 1024 + lane * 16);
#pragma unroll
    for (int mi = 0; mi < MTW; ++mi) {
      const int mt = wgm + mi * RG;
      if (mt < MT) {
#pragma unroll
        for (int q = 0; q < 2; ++q)
          afr[mi][q] = *(const bf16x8*)&XB[(mt * 32 + rA) * SX + kc * 32 + q * 16 + hA * 8];
      }
    }
    __builtin_amdgcn_s_setprio(1);
#pragma unroll
    for (int mi = 0; mi < MTW; ++mi) {
      const int mt = wgm + mi * RG;
      if (mt < MT) {
#pragma unroll
        for (int ni = 0; ni < NTW; ++ni)
#pragma unroll
          for (int q = 0; q < 2; ++q)
            acc[mi][ni] = __builtin_amdgcn_mfma_f32_32x32x16_bf16(
                afr[mi][q], bfr[ni][q], acc[mi][ni], 0, 0, 0);
      }
    }
    __builtin_amdgcn_s_setprio(0);
  }

  // In-place XB modes: ALL waves' XB reads must complete before writing.
  if constexpr (MODE != 3) __syncthreads();

  // epilogue (C/D: col = lane&31, row = (r&3) + 8*(r>>2) + 4*(lane>>5))
#pragma unroll
  for (int mi = 0; mi < MTW; ++mi) {
    const int mt = wgm + mi * RG;
    if (mt >= MT) continue;
#pragma unroll
    for (int ni = 0; ni < NTW; ++ni) {
      const int col = (wgn + ni * CG) * 32 + rA;
#pragma unroll
      for (int r = 0; r < 16; ++r) {
        const int row = mt * 32 + (r & 3) + ((r >> 2) << 3) + (hA << 2);
        const float v = acc[mi][ni][r];
        if constexpr (MODE == 0) {
          if (row < MR) XB[row * SX + col] = f2bf(v);
        } else if constexpr (MODE == 2) {
          if (row < MR) XB[row * SX + col] = f2bf(v * v);
        } else {
          if (row < MR) {
            const size_t o = obase + (size_t)row * K + col;
            outg[o] = fres[o] + v;
          }
        }
      }
    }
  }
}

// ---------------------------------------------------------------------------
// tp phase, 2-channel vectorized (requires (A*K/2) % BLOCK == 0).
// ---------------------------------------------------------------------------
template<int D, int K, int A, int SX>
static __device__ __forceinline__ void tp_pair(int tid, unsigned short* XB) {
  constexpr int DD = D * D;
  constexpr int K2 = K / 2;
  constexpr int PAIRS2 = A * K2;
  static_assert(PAIRS2 % BLOCK == 0, "tp2 coverage");
  const float rsD = rsqrtf((float)D);
#pragma unroll
  for (int it = 0; it < PAIRS2 / BLOCK; ++it) {
    const int p = tid + it * BLOCK;
    const int aa = p / K2, c2 = (p % K2) * 2;
    float hv0[DD], hv1[DD];
#pragma unroll
    for (int r = 0; r < DD; ++r) {
      const unsigned u = *(const unsigned*)&XB[(aa * DD + r) * SX + c2];
      hv0[r] = bf2f((unsigned short)u);
      hv1[r] = bf2f((unsigned short)(u >> 16));
    }
#pragma unroll
    for (int i2 = 0; i2 < D; ++i2)
#pragma unroll
      for (int k2 = 0; k2 < D; ++k2) {
        float s0 = 0.f, s1 = 0.f;
#pragma unroll
        for (int jj = 0; jj < D; ++jj) {
          s0 += hv0[i2 * D + jj] * hv0[jj * D + k2];
          s1 += hv1[i2 * D + jj] * hv1[jj * D + k2];
        }
        *(unsigned*)&XB[(aa * DD + i2 * D + k2) * SX + c2] =
            pk2bf(s0 * rsD, s1 * rsD);
      }
  }
}

// tp phase, scalar one-thread-per-column (requires (A*K) % BLOCK == 0).
template<int D, int K, int A, int SX>
static __device__ __forceinline__ void tp_scalar(int tid, unsigned short* XB) {
  constexpr int DD = D * D;
  constexpr int PAIRS = A * K;
  static_assert(PAIRS % BLOCK == 0, "tp coverage");
  const float rsD = rsqrtf((float)D);
#pragma unroll
  for (int it = 0; it < PAIRS / BLOCK; ++it) {
    const int p = tid + it * BLOCK;
    const int aa = p / K, c = p % K;
    float hv[DD];
#pragma unroll
    for (int r = 0; r < DD; ++r) hv[r] = bf2f(XB[(aa * DD + r) * SX + c]);
#pragma unroll
    for (int i2 = 0; i2 < D; ++i2)
#pragma unroll
      for (int k2 = 0; k2 < D; ++k2) {
        float s = 0.f;
#pragma unroll
        for (int jj = 0; jj < D; ++jj) s += hv[i2 * D + jj] * hv[jj * D + k2];
        XB[(aa * DD + i2 * D + k2) * SX + c] = f2bf(s * rsD);
      }
  }
}

// ---------------------------------------------------------------------------
// Unified per-degree fused CG body (all degrees): LDS = XB only.
//   out = f + linear(tp(linear(rmsnorm(f)*wr, wi)), wo)
// ---------------------------------------------------------------------------
template<int D, int K, int A, int MP, int CG, int CH, int CHB, int MODE1>
__device__ __forceinline__ void cg_body_d(
    int bid, const float* __restrict__ f, const float* __restrict__ wr,
    const char* __restrict__ wiw, const char* __restrict__ wow,
    float* __restrict__ out, unsigned char* SMEM)
{
  constexpr int DD  = D * D;
  constexpr int MR  = A * DD;
  constexpr int SX  = K + 8;
  constexpr int TPA = BLOCK / A;
  constexpr int NF4 = DD * K / 4;
  constexpr int CEIL = (NF4 + TPA - 1) / TPA;

  unsigned short* XB = (unsigned short*)SMEM;

  const int tid = threadIdx.x;
  const int nbase = bid * A;
  const size_t obase = (size_t)nbase * DD * K;

  // ---- P1: reg-stage f, per-atom RMS ----
  const int a = tid / TPA, j = tid % TPA;
  const float* fa = f + (size_t)(nbase + a) * DD * K;
  float4 vreg[CEIL];
  float ss = 0.f;
#pragma unroll
  for (int it = 0; it < CEIL; ++it) {
    const int i = j + it * TPA;
    if (i < NF4) {
      vreg[it] = *(const float4*)&fa[i * 4];
      ss += vreg[it].x * vreg[it].x + vreg[it].y * vreg[it].y +
            vreg[it].z * vreg[it].z + vreg[it].w * vreg[it].w;
    }
  }
#pragma unroll
  for (int o = TPA >> 1; o >= 1; o >>= 1) ss += __shfl_xor(ss, o, 64);
  const float inv = rsqrtf(ss / (float)(DD * K) + 1e-6f);

  // ---- P2: XB = bf16(f * inv * wr), wr straight from global (L2-hot) ----
#pragma unroll
  for (int it = 0; it < CEIL; ++it) {
    const int i = j + it * TPA;
    if (i < NF4) {
      const int e = i * 4, m = e / K, c = e % K;
      const float4 w4 = *(const float4*)&wr[c];
      const unsigned long long pk =
          (unsigned long long)f2bf(vreg[it].x * inv * w4.x) |
          ((unsigned long long)f2bf(vreg[it].y * inv * w4.y) << 16) |
          ((unsigned long long)f2bf(vreg[it].z * inv * w4.z) << 32) |
          ((unsigned long long)f2bf(vreg[it].w * inv * w4.w) << 48);
      *(unsigned long long*)&XB[(a * DD + m) * SX + c] = pk;
    }
  }
  __syncthreads();  // XB(xn) visible to all waves

  // ---- GEMM1: h = xn @ wi -> XB in place (bf16; squared for D==1) ----
  gemm_direct<K, MP, MR, SX, CG, MODE1, CH, CHB>(
      tid, XB, wiw, nullptr, nullptr, 0);
  __syncthreads();  // h visible

  // ---- tp: t = (h h)/sqrt(D) -> XB in place ----
  if constexpr (D > 1) {
    if constexpr ((A * K / 2) % BLOCK == 0) {
      tp_pair<D, K, A, SX>(tid, XB);
    } else {
      tp_scalar<D, K, A, SX>(tid, XB);
    }
    __syncthreads();  // XB(t) ready
  }

  // ---- GEMM2: out = f + t @ wo ----
  gemm_direct<K, MP, MR, SX, CG, 3, CH, CHB>(
      tid, XB, wow, f, out, obase);
}

// ---------------------------------------------------------------------------
// Mega-kernel, degree-interleaved (anti-convoy): counts l0:l1:l2:l3 =
// 625:2500:2500:2500 = 1:4:4:4 -> period-13 pattern x 625 = 8125 blocks.
// LDS = XB only: l0 16896, l1 26112, l2 32256, l3 33280 (union max)
// -> 4 blocks/CU (16 waves). (R17 proven config, restored.)
// ---------------------------------------------------------------------------
__global__ __launch_bounds__(BLOCK, 4) void cg_mega(
    const float* __restrict__ f0, const float* __restrict__ wr0,
    const float* __restrict__ f1, const float* __restrict__ wr1,
    const float* __restrict__ f2, const float* __restrict__ wr2,
    const float* __restrict__ f3, const float* __restrict__ wr3,
    const char* __restrict__ wsB,
    float* __restrict__ out0, float* __restrict__ out1,
    float* __restrict__ out2, float* __restrict__ out3)
{
  __shared__ __align__(16) unsigned char SMEM[33280];
  const int b = blockIdx.x;
  const int p = b / 13, r = b % 13;
  if (r == 0) {
    // <D,K,A,MP,CG,CH,CHB,MODE1>
    cg_body_d<1, 256, 32,  32, 4, 8, 16384, 2>(
        p, f0, wr0, wsB + 0, wsB + 131072, out0, SMEM);
  } else if (r < 5) {
    cg_body_d<3, 128,  8,  96, 4, 4,  8192, 0>(
        p * 4 + (r - 1), f1, wr1, wsB + 262144, wsB + 294912, out1, SMEM);
  } else if (r < 9) {
    cg_body_d<5,  64,  8, 224, 2, 2,  4096, 0>(
        p * 4 + (r - 5), f2, wr2, wsB + 327680, wsB + 335872, out2, SMEM);
  } else {
    cg_body_d<7,  32,  8, 416, 1, 1,  2048, 0>(
        p * 4 + (r - 9), f3, wr3, wsB + 344064, wsB + 346112, out3, SMEM);
  }
}

// ===========================================================================
// Fallback (round-2, proven): used only if ws_size is too small for prep.
// ===========================================================================
template<int K, int MP, int MR, int SX, int SH, int WGM, int WGN, int MTW, int NTW, bool FINAL>
__device__ __forceinline__ void fb_gemm(
    int tid, const unsigned short* __restrict__ XB, float* __restrict__ Hs,
    unsigned short* __restrict__ WTl, const float* __restrict__ Wg,
    const float* __restrict__ fres, float* __restrict__ out, size_t obase)
{
  constexpr int TM = MP / 16;
  constexpr int WSTR = 40;
  const int lane = tid & 63;
  const int wave = tid >> 6;
  const int wgn = wave % WGN;
  const int wgm = wave / WGN;
  const int rl = lane & 15;
  const int kl = (lane >> 4) * 8;
  const int rit = (lane >> 4) * 4;
  const int cit = lane & 15;

  f32x4 acc[MTW][NTW];
#pragma unroll
  for (int mi = 0; mi < MTW; ++mi)
#pragma unroll
    for (int ni = 0; ni < NTW; ++ni) acc[mi][ni] = f32x4{0.f, 0.f, 0.f, 0.f};

  for (int kc = 0; kc < K / 32; ++kc) {
    __syncthreads();
    for (int i = tid; i < 32 * K; i += BLOCK) {
      const int kk = i / K, c = i % K;
      WTl[c * WSTR + kk] = f2bf(Wg[(size_t)(kc * 32 + kk) * K + c]);
    }
    __syncthreads();
    bf16x8 bfr[NTW], afr[MTW];
#pragma unroll
    for (int ni = 0; ni < NTW; ++ni) {
      const int col = (wgn + ni * WGN) * 16 + rl;
      bfr[ni] = *(const bf16x8*)&WTl[col * WSTR + kl];
    }
#pragma unroll
    for (int mi = 0; mi < MTW; ++mi) {
      const int mt = wgm + mi * WGM;
      if (mt < TM) afr[mi] = *(const bf16x8*)&XB[(mt * 16 + rl) * SX + kc * 32 + kl];
    }
#pragma unroll
    for (int mi = 0; mi < MTW; ++mi) {
      const int mt = wgm + mi * WGM;
      if (mt < TM) {
#pragma unroll
        for (int ni = 0; ni < NTW; ++ni)
          acc[mi][ni] = __builtin_amdgcn_mfma_f32_16x16x32_bf16(afr[mi], bfr[ni], acc[mi][ni], 0, 0, 0);
      }
    }
  }
#pragma unroll
  for (int mi = 0; mi < MTW; ++mi) {
    const int mt = wgm + mi * WGM;
    if (mt >= TM) continue;
#pragma unroll
    for (int ni = 0; ni < NTW; ++ni) {
      const int col = (wgn + ni * WGN) * 16 + cit;
#pragma unroll
      for (int r = 0; r < 4; ++r) {
        const int row = mt * 16 + rit + r;
        if constexpr (!FINAL) {
          Hs[row * SH + col] = acc[mi][ni][r];
        } else {
          if (row < MR) {
            const size_t o = obase + (size_t)row * K + col;
            out[o] = fres[o] + acc[mi][ni][r];
          }
        }
      }
    }
  }
}

template<int D, int K, int A, int MP, int WGM, int WGN, int MTW, int NTW>
__global__ __launch_bounds__(BLOCK) void cg_mfma_fb(
    const float* __restrict__ f, const float* __restrict__ wr,
    const float* __restrict__ wi, const float* __restrict__ wo,
    float* __restrict__ out)
{
  constexpr int DD = D * D;
  constexpr int MR = A * DD;
  constexpr int SX = K + 8;
  constexpr int SH = K + 4;
  constexpr int TPA = BLOCK / A;
  constexpr int WSTR = 40;

  __shared__ __align__(16) unsigned short XB[MP * SX];
  __shared__ __align__(16) float H[MP * SH];
  __shared__ __align__(16) unsigned short WTl[K * WSTR];
  __shared__ float s_inv[A];

  const int tid = threadIdx.x;
  const int nbase = blockIdx.x * A;
  const size_t obase = (size_t)nbase * DD * K;

  if constexpr (MP > MR) {
    for (int i = tid; i < (MP - MR) * K; i += BLOCK)
      XB[(MR + i / K) * SX + (i % K)] = 0;
  }
  {
    const int a = tid / TPA, j = tid % TPA;
    const float4* fap = (const float4*)(f + (size_t)(nbase + a) * DD * K);
    constexpr int NF4 = DD * K / 4;
    float ss = 0.f;
    for (int i = j; i < NF4; i += TPA) {
      const float4 v = fap[i];
      const int e = i * 4, m = e / K, c = e % K;
      *(float4*)&H[(a * DD + m) * SH + c] = v;
      ss += v.x * v.x + v.y * v.y + v.z * v.z + v.w * v.w;
    }
#pragma unroll
    for (int o = TPA >> 1; o >= 1; o >>= 1) ss += __shfl_xor(ss, o, 64);
    if (j == 0) s_inv[a] = rsqrtf(ss / (float)(DD * K) + 1e-6f);
  }
  __syncthreads();
  for (int i2 = tid; i2 < MR * K / 2; i2 += BLOCK) {
    const int e = i2 * 2, m = e / K, c = e % K;
    const float2 v = *(const float2*)&H[m * SH + c];
    const float2 wv = *(const float2*)&wr[c];
    const float s = s_inv[m / DD];
    const unsigned lo = f2bf(v.x * s * wv.x);
    const unsigned hi = f2bf(v.y * s * wv.y);
    *(unsigned*)&XB[m * SX + c] = lo | (hi << 16);
  }
  fb_gemm<K, MP, MR, SX, SH, WGM, WGN, MTW, NTW, false>(
      tid, XB, H, WTl, wi, nullptr, nullptr, 0);
  __syncthreads();
  {
    const float rsD = rsqrtf((float)D);
    for (int base = 0; base < A * K; base += BLOCK) {
      const int t2 = base + tid;
      if (t2 < A * K) {
        const int aa = t2 / K, c = t2 % K;
        float hv[DD];
#pragma unroll
        for (int r = 0; r < DD; ++r) hv[r] = H[(aa * DD + r) * SH + c];
#pragma unroll
        for (int i = 0; i < D; ++i)
#pragma unroll
          for (int k2 = 0; k2 < D; ++k2) {
            float s = 0.f;
#pragma unroll
            for (int jj = 0; jj < D; ++jj) s += hv[i * D + jj] * hv[jj * D + k2];
            XB[(aa * DD + i * D + k2) * SX + c] = f2bf(s * rsD);
          }
      }
    }
  }
  fb_gemm<K, MP, MR, SX, SH, WGM, WGN, MTW, NTW, true>(
      tid, XB, nullptr, WTl, wo, f, out, obase);
}

// ===========================================================================
extern "C" void kernel_launch(void* const* d_in, const int* in_sizes, int n_in,
                              void* d_out, int out_size, void* d_ws, size_t ws_size,
                              hipStream_t stream)
{
  (void)in_sizes; (void)n_in; (void)out_size;
  const float* f0  = (const float*)d_in[0];
  const float* wr0 = (const float*)d_in[1];
  const float* wi0 = (const float*)d_in[2];
  const float* wo0 = (const float*)d_in[3];
  const float* f1  = (const float*)d_in[4];
  const float* wr1 = (const float*)d_in[5];
  const float* wi1 = (const float*)d_in[6];
  const float* wo1 = (const float*)d_in[7];
  const float* f2  = (const float*)d_in[8];
  const float* wr2 = (const float*)d_in[9];
  const float* wi2 = (const float*)d_in[10];
  const float* wo2 = (const float*)d_in[11];
  const float* f3  = (const float*)d_in[12];
  const float* wr3 = (const float*)d_in[13];
  const float* wi3 = (const float*)d_in[14];
  const float* wo3 = (const float*)d_in[15];

  float* out  = (float*)d_out;
  float* out0 = out;
  float* out1 = out0 + (size_t)20000 * 256;
  float* out2 = out1 + (size_t)20000 * 1152;
  float* out3 = out2 + (size_t)20000 * 1600;

  if (ws_size >= 348160) {
    unsigned short* wsU = (unsigned short*)d_ws;
    const char* wsB = (const char*)d_ws;
    prep_w<<<170, BLOCK, 0, stream>>>(wi0, wo0, wi1, wo1, wi2, wo2, wi3, wo3, wsU);
    cg_mega<<<8125, BLOCK, 0, stream>>>(
        f0, wr0, f1, wr1, f2, wr2, f3, wr3, wsB, out0, out1, out2, out3);
  } else {
    cg_mfma_fb<1, 256, 32,  32, 1, 4, 2, 4><<< 625, BLOCK, 0, stream>>>(f0, wr0, wi0, wo0, out0);
    cg_mfma_fb<3, 128,  8,  80, 1, 4, 5, 2><<<2500, BLOCK, 0, stream>>>(f1, wr1, wi1, wo1, out1);
    cg_mfma_fb<5,  64,  4, 112, 1, 4, 7, 1><<<5000, BLOCK, 0, stream>>>(f2, wr2, wi2, wo2, out2);
    cg_mfma_fb<7,  32,  4, 208, 4, 1, 4, 2><<<5000, BLOCK, 0, stream>>>(f3, wr3, wi3, wo3, out3);
  }
}